// Round 3
// baseline (338.955 us; speedup 1.0000x reference)
//
#include <hip/hip_runtime.h>
#include <math.h>

#define NCLI 100
#define CPAD 112      // clients padded to 7*16
#define DK   128      // d-rows staged per chunk
#define GBLK 1280     // 5 blocks/CU x 256 CU

typedef short bf16x8 __attribute__((ext_vector_type(8)));  // 8 bf16 (4 VGPRs)
typedef float f32x4  __attribute__((ext_vector_type(4)));

// Swizzled LDS byte offset for (client c, k-offset t). Row stride 256B (128 bf16).
// XOR the 16B-slot index (bits 4-7) by c&15: breaks the 256B-stride bank conflict
// on fragment reads; preserves 16B-slot contiguity (reads/writes never straddle).
__device__ __forceinline__ int lds_byte(int c, int t) {
    return c * 256 + ((t * 2) ^ ((c & 15) << 4));
}

// fp32 -> bf16 (RNE), bit pattern as ushort
__device__ __forceinline__ unsigned short f2bf(float x) {
    unsigned u = __float_as_uint(x);
    unsigned r = (u + 0x7fffu + ((u >> 16) & 1u)) >> 16;
    return (unsigned short)r;
}

// ---------------- tiny zero kernel (replaces hipMemsetAsync graph node) ----------------
__global__ void zero_kernel(float4* __restrict__ p, int n4) {
    int i = blockIdx.x * blockDim.x + threadIdx.x;
    if (i < n4) p[i] = make_float4(0.f, 0.f, 0.f, 0.f);
}

// Wave W owns 16x16 output tiles: row a=W, b=W..6 (7-W tiles) and, for W>0,
// row a=7-W, b=7-W..6 (W tiles). Exactly 7 tiles per wave, A-frags {W, 7-W}.
template <int W>
__device__ __forceinline__ void compute_chunk(const char* base, f32x4 acc[7]) {
    const int lane = threadIdx.x & 63;
    const int lrow = lane & 15;        // row/col within tile
    const int kgrp = lane >> 4;        // k-group 0..3 (8 bf16 each)
    constexpr int NB = 7 - W;          // b = W..6
#pragma unroll
    for (int kk = 0; kk < DK; kk += 32) {
        const int kb = kk + kgrp * 8;
        bf16x8 bfr[NB];
#pragma unroll
        for (int j = 0; j < NB; ++j)
            bfr[j] = *(const bf16x8*)(base + lds_byte((W + j) * 16 + lrow, kb));
        bf16x8 a0 = *(const bf16x8*)(base + lds_byte(W * 16 + lrow, kb));
#pragma unroll
        for (int j = 0; j < NB; ++j)
            acc[j] = __builtin_amdgcn_mfma_f32_16x16x32_bf16(a0, bfr[j], acc[j], 0, 0, 0);
        if constexpr (W > 0) {
            bf16x8 a1 = *(const bf16x8*)(base + lds_byte((7 - W) * 16 + lrow, kb));
#pragma unroll
            for (int j = 0; j < W; ++j)
                acc[NB + j] = __builtin_amdgcn_mfma_f32_16x16x32_bf16(
                    a1, bfr[NB - W + j], acc[NB + j], 0, 0, 0);
        }
    }
}

template <int W>
__device__ __forceinline__ void store_acc(float* __restrict__ G, const f32x4 acc[7]) {
    const int lane = threadIdx.x & 63;
    const int cn = lane & 15;                 // output col within tile
    const int r0 = (lane >> 4) * 4;           // output row base within tile
#pragma unroll
    for (int j = 0; j < 7 - W; ++j) {         // tiles (W, W+j)
#pragma unroll
        for (int r = 0; r < 4; ++r) {
            int i = W * 16 + r0 + r;
            int k = (W + j) * 16 + cn;
            if (i < NCLI && k < NCLI) atomicAdd(&G[i * NCLI + k], acc[j][r]);
        }
    }
    if constexpr (W > 0) {
#pragma unroll
        for (int j = 0; j < W; ++j) {         // tiles (7-W, 7-W+j)
#pragma unroll
            for (int r = 0; r < 4; ++r) {
                int i = (7 - W) * 16 + r0 + r;
                int k = (7 - W + j) * 16 + cn;
                if (i < NCLI && k < NCLI) atomicAdd(&G[i * NCLI + k], acc[7 - W + j][r]);
            }
        }
    }
}

// ---------------- MFMA Gram: G[i][k] = sum_d A[d][i]*A[d][k] (upper triangle) ----------------
__global__ __launch_bounds__(256, 5) void gram_mfma(const float* __restrict__ A,
                                                    float* __restrict__ G,
                                                    long dtot, int nchunks) {
    __shared__ uint4 ldsq[CPAD * 16];   // 112 x 256B = 28672 B -> 5 blocks/CU
    char* base = (char*)ldsq;
    const int tid = threadIdx.x;
    const int wid = tid >> 6;

    // zero the pad-client rows 100..111 once (whole rows zero, swizzle irrelevant)
    for (int u = tid; u < (CPAD - NCLI) * 64; u += 256)
        ((unsigned*)(base + NCLI * 256))[u] = 0u;

    f32x4 acc[7];
#pragma unroll
    for (int q = 0; q < 7; ++q) acc[q] = (f32x4)(0.0f);

    for (int chunk = blockIdx.x; chunk < nchunks; chunk += gridDim.x) {
        const long d0 = (long)chunk * DK;
        __syncthreads();  // LDS reuse guard
        // stage: 128 rows x 100 cols fp32 -> bf16, transposed to [client][t]
        for (int u = tid; u < 32 * 25; u += 256) {
            int rg = u / 25;            // 4-row group 0..31
            int cg = u - rg * 25;       // 4-col group 0..24
            float4 v[4];
#pragma unroll
            for (int r = 0; r < 4; ++r) {
                long dr = d0 + rg * 4 + r;
                if (dr < dtot)
                    v[r] = *(const float4*)(A + dr * NCLI + cg * 4);
                else
                    v[r] = make_float4(0.f, 0.f, 0.f, 0.f);
            }
#pragma unroll
            for (int j = 0; j < 4; ++j) {
                int c = cg * 4 + j;
                ushort4 p;
                p.x = f2bf(((const float*)&v[0])[j]);
                p.y = f2bf(((const float*)&v[1])[j]);
                p.z = f2bf(((const float*)&v[2])[j]);
                p.w = f2bf(((const float*)&v[3])[j]);
                *(ushort4*)(base + lds_byte(c, rg * 4)) = p;  // 8B, one 16B slot
            }
        }
        __syncthreads();
        if (wid == 0)      compute_chunk<0>(base, acc);
        else if (wid == 1) compute_chunk<1>(base, acc);
        else if (wid == 2) compute_chunk<2>(base, acc);
        else               compute_chunk<3>(base, acc);
    }

    if (wid == 0)      store_acc<0>(G, acc);
    else if (wid == 1) store_acc<1>(G, acc);
    else if (wid == 2) store_acc<2>(G, acc);
    else               store_acc<3>(G, acc);
}

// ---------------- Weights kernel: full FoolsGold weight computation, single block ----------------
__global__ __launch_bounds__(128) void weights_kernel(const float* __restrict__ G,
                                                      float* __restrict__ w) {
    __shared__ float cs[NCLI][NCLI + 1];
    __shared__ float nrm[NCLI], maxcs[NCLI], wv[NCLI];
    __shared__ float red[2];
    const int t = threadIdx.x;

    if (t < NCLI) {
        float g = G[t * NCLI + t];
        nrm[t] = fmaxf(sqrtf(g), 1e-12f);
    }
    __syncthreads();

    for (int idx = t; idx < NCLI * NCLI; idx += 128) {
        int i = idx / NCLI;
        int j = idx - i * NCLI;
        int a = i < j ? i : j;
        int b = i < j ? j : i;
        float c = G[a * NCLI + b] / (nrm[i] * nrm[j]);
        if (i == j) c -= 1.0f;
        cs[i][j] = c;
    }
    __syncthreads();

    if (t < NCLI) {
        float m = -1e30f;
        for (int j = 0; j < NCLI; ++j) m = fmaxf(m, cs[t][j]);
        maxcs[t] = m;
    }
    __syncthreads();

    if (t < NCLI) {
        float mi = maxcs[t];
        float m = -1e30f;
        for (int j = 0; j < NCLI; ++j) {
            float v = cs[t][j];
            float mj = maxcs[j];
            if (t != j && mi < mj) v *= mi / mj;  // pardoning
            m = fmaxf(m, v);
        }
        float x = 1.0f - m;
        x = fminf(fmaxf(x, 0.0f), 1.0f);
        wv[t] = x;
    }
    __syncthreads();

    if (t == 0) {
        float m = 0.0f;
        for (int i = 0; i < NCLI; ++i) m = fmaxf(m, wv[i]);
        red[0] = m;
    }
    __syncthreads();

    if (t < NCLI) {
        float x = wv[t] / red[0];
        if (x == 1.0f) x = 0.99f;
        float l = logf(x / (1.0f - x)) + 0.5f;
        float flag = isinf(l) ? 1.0f : 0.0f;   // torch: wv[isinf(wv)+wv > 1] = 1
        l = (flag + l > 1.0f) ? 1.0f : l;
        l = (l < 0.0f) ? 0.0f : l;
        wv[t] = l;
    }
    __syncthreads();

    if (t == 0) {
        float s = 0.0f;
        for (int i = 0; i < NCLI; ++i) s += wv[i];
        red[1] = s;
    }
    __syncthreads();

    if (t < NCLI) w[t] = wv[t] / red[1];
}

// ---------------- Output kernel: out[j] = dot(A[j][:], w), LDS-staged coalesced ----------------
// One wave per block; stages 64 rows (25.6 KB) with coalesced float4 loads, then
// per-lane dot from LDS (row stride 100 words -> bank group = lane%8, conflict-free b128).
__global__ __launch_bounds__(64) void out_kernel(const float* __restrict__ A,
                                                 const float* __restrict__ w,
                                                 float* __restrict__ out, int d) {
    __shared__ float lds[64 * NCLI];   // 25.6 KB -> 6 blocks/CU
    __shared__ float ws[NCLI];
    const int lane = threadIdx.x;
    if (lane < NCLI / 2) ((float2*)ws)[lane] = ((const float2*)w)[lane];
    __syncthreads();

    const long rb = (long)blockIdx.x * 64;
    if (rb >= d) return;
    const long total4 = (long)d * NCLI / 4;   // float4 count in A
    const float4* src = (const float4*)A + rb * (NCLI / 4);
#pragma unroll
    for (int q = 0; q < 25; ++q) {
        long gi = rb * (NCLI / 4) + q * 64 + lane;
        ((float4*)lds)[q * 64 + lane] =
            (gi < total4) ? src[q * 64 + lane] : make_float4(0.f, 0.f, 0.f, 0.f);
    }
    __syncthreads();

    if (rb + lane < d) {
        const float4* row = (const float4*)(lds + lane * NCLI);
        const float4* wf = (const float4*)ws;
        float s = 0.0f;
#pragma unroll
        for (int q = 0; q < NCLI / 4; ++q) {
            float4 v = row[q];
            float4 ww = wf[q];
            s += v.x * ww.x + v.y * ww.y + v.z * ww.z + v.w * ww.w;
        }
        out[rb + lane] = s;
    }
}

extern "C" void kernel_launch(void* const* d_in, const int* in_sizes, int n_in,
                              void* d_out, int out_size, void* d_ws, size_t ws_size,
                              hipStream_t stream) {
    const float* A = (const float*)d_in[0];
    float* out = (float*)d_out;
    const int d = in_sizes[0] / NCLI;

    float* G = (float*)d_ws;           // 100*100 f32 (upper triangle used)
    float* w = G + NCLI * NCLI;        // 100 f32 weights

    // zero G (custom kernel: hipMemsetAsync graph node showed 238us anomalies)
    const int n4 = (NCLI * NCLI) / 4;  // 2500 float4
    zero_kernel<<<(n4 + 255) / 256, 256, 0, stream>>>((float4*)G, n4);

    const int nchunks = (d + DK - 1) / DK;
    const int gblocks = nchunks < GBLK ? nchunks : GBLK;
    gram_mfma<<<gblocks, 256, 0, stream>>>(A, G, (long)d, nchunks);

    weights_kernel<<<1, 128, 0, stream>>>(G, w);

    const int oblocks = (d + 63) / 64;  // one-shot blocks, dynamic balance
    out_kernel<<<oblocks, 64, 0, stream>>>(A, w, out, d);
}

// Round 4
// 271.722 us; speedup vs baseline: 1.2474x; 1.2474x over previous
//
#include <hip/hip_runtime.h>
#include <math.h>

#define NCLI 100
#define CPAD 112      // clients padded to 7*16
#define DK   128      // d-rows staged per chunk
#define GBLK 1024     // 4 blocks/CU x 256 CU

typedef short bf16x8 __attribute__((ext_vector_type(8)));  // 8 bf16 (4 VGPRs)
typedef float f32x4  __attribute__((ext_vector_type(4)));

// Swizzled LDS byte offset for (client c, k-offset t). Row stride 256B (128 bf16).
// XOR the 16B-slot index (bits 4-7) by c&15: breaks the 256B-stride bank conflict
// on fragment reads; preserves 16B-slot contiguity (reads/writes never straddle).
__device__ __forceinline__ int lds_byte(int c, int t) {
    return c * 256 + ((t * 2) ^ ((c & 15) << 4));
}

// fp32 -> bf16 (RNE), bit pattern as ushort
__device__ __forceinline__ unsigned short f2bf(float x) {
    unsigned u = __float_as_uint(x);
    unsigned r = (u + 0x7fffu + ((u >> 16) & 1u)) >> 16;
    return (unsigned short)r;
}

// ---------------- tiny zero kernel (graph-safe G clear) ----------------
__global__ void zero_kernel(float4* __restrict__ p, int n4) {
    int i = blockIdx.x * blockDim.x + threadIdx.x;
    if (i < n4) p[i] = make_float4(0.f, 0.f, 0.f, 0.f);
}

// Wave W owns 16x16 output tiles: row a=W, b=W..6 (7-W tiles) and, for W>0,
// row a=7-W, b=7-W..6 (W tiles). Exactly 7 tiles per wave, A-frags {W, 7-W}.
template <int W>
__device__ __forceinline__ void compute_chunk(const char* base, f32x4 acc[7]) {
    const int lane = threadIdx.x & 63;
    const int lrow = lane & 15;        // row/col within tile
    const int kgrp = lane >> 4;        // k-group 0..3 (8 bf16 each)
    constexpr int NB = 7 - W;          // b = W..6
#pragma unroll
    for (int kk = 0; kk < DK; kk += 32) {
        const int kb = kk + kgrp * 8;
        bf16x8 bfr[NB];
#pragma unroll
        for (int j = 0; j < NB; ++j)
            bfr[j] = *(const bf16x8*)(base + lds_byte((W + j) * 16 + lrow, kb));
        bf16x8 a0 = *(const bf16x8*)(base + lds_byte(W * 16 + lrow, kb));
#pragma unroll
        for (int j = 0; j < NB; ++j)
            acc[j] = __builtin_amdgcn_mfma_f32_16x16x32_bf16(a0, bfr[j], acc[j], 0, 0, 0);
        if constexpr (W > 0) {
            bf16x8 a1 = *(const bf16x8*)(base + lds_byte((7 - W) * 16 + lrow, kb));
#pragma unroll
            for (int j = 0; j < W; ++j)
                acc[NB + j] = __builtin_amdgcn_mfma_f32_16x16x32_bf16(
                    a1, bfr[NB - W + j], acc[NB + j], 0, 0, 0);
        }
    }
}

template <int W>
__device__ __forceinline__ void store_acc(float* __restrict__ G, const f32x4 acc[7]) {
    const int lane = threadIdx.x & 63;
    const int cn = lane & 15;                 // output col within tile
    const int r0 = (lane >> 4) * 4;           // output row base within tile
#pragma unroll
    for (int j = 0; j < 7 - W; ++j) {         // tiles (W, W+j)
#pragma unroll
        for (int r = 0; r < 4; ++r) {
            int i = W * 16 + r0 + r;
            int k = (W + j) * 16 + cn;
            if (i < NCLI && k < NCLI) atomicAdd(&G[i * NCLI + k], acc[j][r]);
        }
    }
    if constexpr (W > 0) {
#pragma unroll
        for (int j = 0; j < W; ++j) {         // tiles (7-W, 7-W+j)
#pragma unroll
            for (int r = 0; r < 4; ++r) {
                int i = (7 - W) * 16 + r0 + r;
                int k = (7 - W + j) * 16 + cn;
                if (i < NCLI && k < NCLI) atomicAdd(&G[i * NCLI + k], acc[7 - W + j][r]);
            }
        }
    }
}

// ---------------- MFMA Gram: G[i][k] = sum_d A[d][i]*A[d][k] (upper triangle) ----------------
__global__ __launch_bounds__(256, 4) void gram_mfma(const float* __restrict__ A,
                                                    float* __restrict__ G,
                                                    long dtot, int nchunks) {
    __shared__ uint4 ldsq[CPAD * 16];   // 112 x 256B = 28672 B
    char* base = (char*)ldsq;
    const int tid = threadIdx.x;
    const int wid = tid >> 6;

    // zero the pad-client rows 100..111 once (whole rows zero, swizzle irrelevant)
    for (int u = tid; u < (CPAD - NCLI) * 64; u += 256)
        ((unsigned*)(base + NCLI * 256))[u] = 0u;

    f32x4 acc[7];
#pragma unroll
    for (int q = 0; q < 7; ++q) acc[q] = (f32x4)(0.0f);

    for (int chunk = blockIdx.x; chunk < nchunks; chunk += gridDim.x) {
        const long d0 = (long)chunk * DK;
        __syncthreads();  // LDS reuse guard
        // stage: 128 rows x 100 cols fp32 -> bf16, transposed to [client][t]
        for (int u = tid; u < 32 * 25; u += 256) {
            int rg = u / 25;            // 4-row group 0..31
            int cg = u - rg * 25;       // 4-col group 0..24
            float4 v[4];
#pragma unroll
            for (int r = 0; r < 4; ++r) {
                long dr = d0 + rg * 4 + r;
                if (dr < dtot)
                    v[r] = *(const float4*)(A + dr * NCLI + cg * 4);
                else
                    v[r] = make_float4(0.f, 0.f, 0.f, 0.f);
            }
#pragma unroll
            for (int j = 0; j < 4; ++j) {
                int c = cg * 4 + j;
                ushort4 p;
                p.x = f2bf(((const float*)&v[0])[j]);
                p.y = f2bf(((const float*)&v[1])[j]);
                p.z = f2bf(((const float*)&v[2])[j]);
                p.w = f2bf(((const float*)&v[3])[j]);
                *(ushort4*)(base + lds_byte(c, rg * 4)) = p;  // 8B, one 16B slot
            }
        }
        __syncthreads();
        if (wid == 0)      compute_chunk<0>(base, acc);
        else if (wid == 1) compute_chunk<1>(base, acc);
        else if (wid == 2) compute_chunk<2>(base, acc);
        else               compute_chunk<3>(base, acc);
    }

    if (wid == 0)      store_acc<0>(G, acc);
    else if (wid == 1) store_acc<1>(G, acc);
    else if (wid == 2) store_acc<2>(G, acc);
    else               store_acc<3>(G, acc);
}

// ---------------- Weights kernel: full FoolsGold weight computation, single block ----------------
__global__ __launch_bounds__(128) void weights_kernel(const float* __restrict__ G,
                                                      float* __restrict__ w) {
    __shared__ float cs[NCLI][NCLI + 1];
    __shared__ float nrm[NCLI], maxcs[NCLI], wv[NCLI];
    __shared__ float red[2];
    const int t = threadIdx.x;

    if (t < NCLI) {
        float g = G[t * NCLI + t];
        nrm[t] = fmaxf(sqrtf(g), 1e-12f);
    }
    __syncthreads();

    for (int idx = t; idx < NCLI * NCLI; idx += 128) {
        int i = idx / NCLI;
        int j = idx - i * NCLI;
        int a = i < j ? i : j;
        int b = i < j ? j : i;
        float c = G[a * NCLI + b] / (nrm[i] * nrm[j]);
        if (i == j) c -= 1.0f;
        cs[i][j] = c;
    }
    __syncthreads();

    if (t < NCLI) {
        float m = -1e30f;
        for (int j = 0; j < NCLI; ++j) m = fmaxf(m, cs[t][j]);
        maxcs[t] = m;
    }
    __syncthreads();

    if (t < NCLI) {
        float mi = maxcs[t];
        float m = -1e30f;
        for (int j = 0; j < NCLI; ++j) {
            float v = cs[t][j];
            float mj = maxcs[j];
            if (t != j && mi < mj) v *= mi / mj;  // pardoning
            m = fmaxf(m, v);
        }
        float x = 1.0f - m;
        x = fminf(fmaxf(x, 0.0f), 1.0f);
        wv[t] = x;
    }
    __syncthreads();

    if (t == 0) {
        float m = 0.0f;
        for (int i = 0; i < NCLI; ++i) m = fmaxf(m, wv[i]);
        red[0] = m;
    }
    __syncthreads();

    if (t < NCLI) {
        float x = wv[t] / red[0];
        if (x == 1.0f) x = 0.99f;
        float l = logf(x / (1.0f - x)) + 0.5f;
        float flag = isinf(l) ? 1.0f : 0.0f;   // torch: wv[isinf(wv)+wv > 1] = 1
        l = (flag + l > 1.0f) ? 1.0f : l;
        l = (l < 0.0f) ? 0.0f : l;
        wv[t] = l;
    }
    __syncthreads();

    if (t == 0) {
        float s = 0.0f;
        for (int i = 0; i < NCLI; ++i) s += wv[i];
        red[1] = s;
    }
    __syncthreads();

    if (t < NCLI) w[t] = wv[t] / red[1];
}

// ---------------- Output kernel: out[j] = dot(A[j][:], w) ----------------
// Direct per-lane-row float4 loads (round-2 structure: high TLP, MSHR-window line
// reuse). REVERSED block->row mapping: gram streamed A head->tail, so L3 holds
// A's tail; processing tail-first converts up to ~256MB of reads into L3 hits.
__global__ __launch_bounds__(256) void out_kernel(const float* __restrict__ A,
                                                  const float* __restrict__ w,
                                                  float* __restrict__ out, int d,
                                                  int nblocks) {
    __shared__ float4 w4[NCLI / 4];
    if (threadIdx.x < NCLI / 4) w4[threadIdx.x] = ((const float4*)w)[threadIdx.x];
    __syncthreads();
    const long rb = (long)(nblocks - 1 - blockIdx.x) * 256;  // tail-first
    const long j = rb + threadIdx.x;
    if (j >= d) return;
    const float4* row = (const float4*)(A + j * NCLI);  // 400B rows, 16B aligned
    float s0 = 0.0f, s1 = 0.0f;
#pragma unroll
    for (int q = 0; q < NCLI / 8; ++q) {   // 12 pairs
        float4 v0 = row[2 * q];
        float4 ww0 = w4[2 * q];
        float4 v1 = row[2 * q + 1];
        float4 ww1 = w4[2 * q + 1];
        s0 += v0.x * ww0.x + v0.y * ww0.y + v0.z * ww0.z + v0.w * ww0.w;
        s1 += v1.x * ww1.x + v1.y * ww1.y + v1.z * ww1.z + v1.w * ww1.w;
    }
    {
        float4 v = row[24];
        float4 ww = w4[24];
        s0 += v.x * ww.x + v.y * ww.y + v.z * ww.z + v.w * ww.w;
    }
    out[j] = s0 + s1;
}

extern "C" void kernel_launch(void* const* d_in, const int* in_sizes, int n_in,
                              void* d_out, int out_size, void* d_ws, size_t ws_size,
                              hipStream_t stream) {
    const float* A = (const float*)d_in[0];
    float* out = (float*)d_out;
    const int d = in_sizes[0] / NCLI;

    float* G = (float*)d_ws;           // 100*100 f32 (upper triangle used)
    float* w = G + NCLI * NCLI;        // 100 f32 weights

    const int n4 = (NCLI * NCLI) / 4;  // 2500 float4
    zero_kernel<<<(n4 + 255) / 256, 256, 0, stream>>>((float4*)G, n4);

    const int nchunks = (d + DK - 1) / DK;
    const int gblocks = nchunks < GBLK ? nchunks : GBLK;
    gram_mfma<<<gblocks, 256, 0, stream>>>(A, G, (long)d, nchunks);

    weights_kernel<<<1, 128, 0, stream>>>(G, w);

    const int oblocks = (d + 255) / 256;
    out_kernel<<<oblocks, 256, 0, stream>>>(A, w, out, d, oblocks);
}